// Round 1
// baseline (526.031 us; speedup 1.0000x reference)
//
#include <hip/hip_runtime.h>
#include <cstdint>

#define S_LEN   2048
#define D_MODEL 1024
#define NHEAD   16
#define DHEAD   64
#define BATCH   2
#define M_ROWS  (BATCH * S_LEN)   // 4096

typedef __attribute__((ext_vector_type(8))) short bf16x8;
typedef __attribute__((ext_vector_type(4))) float f32x4;

__device__ __forceinline__ unsigned short f2bf(float f) {
    union { float f; uint32_t u; } v; v.f = f;
    uint32_t u = v.u;
    return (unsigned short)((u + 0x7FFFu + ((u >> 16) & 1u)) >> 16);
}

__device__ __forceinline__ void gload_lds16(const void* g, void* l) {
    __builtin_amdgcn_global_load_lds(
        (const __attribute__((address_space(1))) void*)g,
        (__attribute__((address_space(3))) void*)l, 16, 0, 0);
}

// ---------------- f32 -> bf16 convert ----------------
__global__ void cvt_kernel(const float* __restrict__ src,
                           unsigned short* __restrict__ dst, int n4) {
    int i = blockIdx.x * blockDim.x + threadIdx.x;
    if (i >= n4) return;
    float4 v = reinterpret_cast<const float4*>(src)[i];
    ushort4 o;
    o.x = f2bf(v.x); o.y = f2bf(v.y); o.z = f2bf(v.z); o.w = f2bf(v.w);
    reinterpret_cast<ushort4*>(dst)[i] = o;
}

// ---------------- GEMM: C = A @ Bw^T + bias ----------------
// A [M][K] bf16 row-major, Bw [N][K] bf16 row-major.
// MODE 0: out bf16, head-major [BH][S][DHEAD]   (Q, K proj; m=b*S+s, n=h*64+d)
// MODE 1: out bf16, V-transposed [BH][DHEAD][S] (m=d_full, n=b*S+s; bias[m])
// MODE 2: out f32 plain [M][N]                  (final y)
template<int MODE>
__global__ __launch_bounds__(256) void gemm_bt(
    const unsigned short* __restrict__ A,
    const unsigned short* __restrict__ Bw,
    const float* __restrict__ bias,
    void* __restrict__ Cout,
    int M, int N, int K)
{
    __shared__ unsigned short lA[128 * 32];
    __shared__ unsigned short lB[128 * 32];
    const int tid  = threadIdx.x;
    const int lane = tid & 63;
    const int w    = tid >> 6;
    const int wr   = w >> 1, wc = w & 1;
    const int g    = lane >> 4, r16 = lane & 15;
    const int brow = blockIdx.y * 128;
    const int bcol = blockIdx.x * 128;

    f32x4 acc[4][4];
#pragma unroll
    for (int i = 0; i < 4; ++i)
#pragma unroll
        for (int j = 0; j < 4; ++j) acc[i][j] = (f32x4){0.f, 0.f, 0.f, 0.f};

    const int rA0 = tid >> 2;          // staging row (it=0)
    const int cc  = (tid & 3) * 8;     // staging col

    for (int kk = 0; kk < K; kk += 32) {
#pragma unroll
        for (int it = 0; it < 2; ++it) {
            int r = it * 64 + rA0;
            gload_lds16(A  + (size_t)(brow + r) * K + kk + cc, &lA[r * 32 + cc]);
            gload_lds16(Bw + (size_t)(bcol + r) * K + kk + cc, &lB[r * 32 + cc]);
        }
        __syncthreads();
        bf16x8 af[4], bfr[4];
#pragma unroll
        for (int i = 0; i < 4; ++i)
            af[i] = *reinterpret_cast<const bf16x8*>(&lA[(wr * 64 + i * 16 + r16) * 32 + g * 8]);
#pragma unroll
        for (int j = 0; j < 4; ++j)
            bfr[j] = *reinterpret_cast<const bf16x8*>(&lB[(wc * 64 + j * 16 + r16) * 32 + g * 8]);
#pragma unroll
        for (int i = 0; i < 4; ++i)
#pragma unroll
            for (int j = 0; j < 4; ++j)
                acc[i][j] = __builtin_amdgcn_mfma_f32_16x16x32_bf16(af[i], bfr[j], acc[i][j], 0, 0, 0);
        __syncthreads();
    }

#pragma unroll
    for (int i = 0; i < 4; ++i) {
#pragma unroll
        for (int j = 0; j < 4; ++j) {
            const int n = bcol + wc * 64 + j * 16 + r16;
#pragma unroll
            for (int rr = 0; rr < 4; ++rr) {
                const int m = brow + wr * 64 + i * 16 + g * 4 + rr;
                float val = acc[i][j][rr];
                if (MODE == 0) {
                    val += bias[n];
                    int b = m >> 11, s = m & 2047;
                    int h = n >> 6,  d = n & 63;
                    ((unsigned short*)Cout)[(((size_t)(b * NHEAD + h)) * S_LEN + s) * DHEAD + d] = f2bf(val);
                } else if (MODE == 1) {
                    val += bias[m];
                    int h = m >> 6,  d = m & 63;
                    int b = n >> 11, s = n & 2047;
                    ((unsigned short*)Cout)[(((size_t)(b * NHEAD + h)) * DHEAD + d) * S_LEN + s] = f2bf(val);
                } else {
                    val += bias[n];
                    ((float*)Cout)[(size_t)m * D_MODEL + n] = val;
                }
            }
        }
    }
}

// ---------------- fused causal attention ----------------
// grid: (S/64 q-tiles, B*H). 4 waves x 16 q-rows. Two-pass online softmax.
// Writes f32 probs to attn_out [BH][S][S], bf16 context to ctx [B*S][D].
__global__ __launch_bounds__(256) void attn_kernel(
    const unsigned short* __restrict__ Qh,
    const unsigned short* __restrict__ Kh,
    const unsigned short* __restrict__ Vt,
    float* __restrict__ attn_out,
    unsigned short* __restrict__ ctx)
{
    __shared__ unsigned short pLds[4][16 * 80];   // per-wave P tile, stride 80 (bank-safe)
    const int tid  = threadIdx.x;
    const int lane = tid & 63;
    const int w    = tid >> 6;
    const int g    = lane >> 4, r16 = lane & 15;
    const int bh   = blockIdx.y;
    const int b    = bh >> 4, h = bh & 15;
    const int q0   = blockIdx.x * 64;
    const int qw   = q0 + w * 16;

    const unsigned short* Qp = Qh + ((size_t)bh * S_LEN + qw) * DHEAD;
    const unsigned short* Kp = Kh + (size_t)bh * S_LEN * DHEAD;
    const unsigned short* Vp = Vt + (size_t)bh * DHEAD * S_LEN;
    float* arow = attn_out + (size_t)bh * S_LEN * S_LEN;

    bf16x8 qf[2];
#pragma unroll
    for (int d2 = 0; d2 < 2; ++d2)
        qf[d2] = *reinterpret_cast<const bf16x8*>(Qp + (size_t)r16 * DHEAD + d2 * 32 + g * 8);

    const float scale = 0.125f;   // 1/sqrt(64)
    float m_run[4], l_run[4];
#pragma unroll
    for (int rr = 0; rr < 4; ++rr) { m_run[rr] = -INFINITY; l_run[rr] = 0.f; }

    const int lastT = blockIdx.x;

    // ---- pass 1: row max + exp-sum ----
    for (int kt = 0; kt <= lastT; ++kt) {
        const int kb = kt * 64;
        f32x4 sf[4];
#pragma unroll
        for (int nt = 0; nt < 4; ++nt) sf[nt] = (f32x4){0, 0, 0, 0};
#pragma unroll
        for (int d2 = 0; d2 < 2; ++d2)
#pragma unroll
            for (int nt = 0; nt < 4; ++nt) {
                bf16x8 kf = *reinterpret_cast<const bf16x8*>(
                    Kp + (size_t)(kb + nt * 16 + r16) * DHEAD + d2 * 32 + g * 8);
                sf[nt] = __builtin_amdgcn_mfma_f32_16x16x32_bf16(qf[d2], kf, sf[nt], 0, 0, 0);
            }
#pragma unroll
        for (int rr = 0; rr < 4; ++rr) {
            const int q = qw + g * 4 + rr;
            float vals[4]; float tmax = -INFINITY;
#pragma unroll
            for (int nt = 0; nt < 4; ++nt) {
                int k = kb + nt * 16 + r16;
                float s = sf[nt][rr] * scale;
                s = (k <= q) ? s : -INFINITY;
                vals[nt] = s;
                tmax = fmaxf(tmax, s);
            }
#pragma unroll
            for (int msk = 1; msk < 16; msk <<= 1) tmax = fmaxf(tmax, __shfl_xor(tmax, msk));
            float mn = fmaxf(m_run[rr], tmax);
            float sum = 0.f;
#pragma unroll
            for (int nt = 0; nt < 4; ++nt) sum += __expf(vals[nt] - mn);
#pragma unroll
            for (int msk = 1; msk < 16; msk <<= 1) sum += __shfl_xor(sum, msk);
            l_run[rr] = l_run[rr] * __expf(m_run[rr] - mn) + sum;
            m_run[rr] = mn;
        }
    }

    float inv_l[4];
#pragma unroll
    for (int rr = 0; rr < 4; ++rr) inv_l[rr] = 1.f / l_run[rr];

    f32x4 of[4];
#pragma unroll
    for (int nt = 0; nt < 4; ++nt) of[nt] = (f32x4){0, 0, 0, 0};

    unsigned short* pl = pLds[w];

    // ---- pass 2: probs out + P@V ----
    for (int kt = 0; kt <= lastT; ++kt) {
        const int kb = kt * 64;
        f32x4 sf[4];
#pragma unroll
        for (int nt = 0; nt < 4; ++nt) sf[nt] = (f32x4){0, 0, 0, 0};
#pragma unroll
        for (int d2 = 0; d2 < 2; ++d2)
#pragma unroll
            for (int nt = 0; nt < 4; ++nt) {
                bf16x8 kf = *reinterpret_cast<const bf16x8*>(
                    Kp + (size_t)(kb + nt * 16 + r16) * DHEAD + d2 * 32 + g * 8);
                sf[nt] = __builtin_amdgcn_mfma_f32_16x16x32_bf16(qf[d2], kf, sf[nt], 0, 0, 0);
            }
#pragma unroll
        for (int rr = 0; rr < 4; ++rr) {
            const int q = qw + g * 4 + rr;
            float* dst = arow + (size_t)q * S_LEN + kb + r16;
#pragma unroll
            for (int nt = 0; nt < 4; ++nt) {
                int k = kb + nt * 16 + r16;
                float p = 0.f;
                if (k <= q) p = __expf(sf[nt][rr] * scale - m_run[rr]) * inv_l[rr];
                dst[nt * 16] = p;
                pl[(g * 4 + rr) * 80 + nt * 16 + r16] = f2bf(p);
            }
        }
        __syncthreads();   // uniform across block; orders P writes vs frag reads
#pragma unroll
        for (int kh = 0; kh < 2; ++kh) {
            bf16x8 pa = *reinterpret_cast<const bf16x8*>(&pl[r16 * 80 + kh * 32 + g * 8]);
#pragma unroll
            for (int nt = 0; nt < 4; ++nt) {
                bf16x8 vf = *reinterpret_cast<const bf16x8*>(
                    Vp + (size_t)(nt * 16 + r16) * S_LEN + kb + kh * 32 + g * 8);
                of[nt] = __builtin_amdgcn_mfma_f32_16x16x32_bf16(pa, vf, of[nt], 0, 0, 0);
            }
        }
        __syncthreads();
    }

    // zero-fill the strict upper region beyond the diagonal tile
    const int z0 = (lastT + 1) * 64;
    const float4 z4 = make_float4(0.f, 0.f, 0.f, 0.f);
    for (int r = 0; r < 16; ++r) {
        float* dst = arow + (size_t)(qw + r) * S_LEN;
        for (int c = z0 + lane * 4; c < S_LEN; c += 256)
            *reinterpret_cast<float4*>(dst + c) = z4;
    }

    // context out [B*S][D] bf16
#pragma unroll
    for (int nt = 0; nt < 4; ++nt) {
        const int d = nt * 16 + r16;
#pragma unroll
        for (int rr = 0; rr < 4; ++rr) {
            const int q = qw + g * 4 + rr;
            ctx[((size_t)b * S_LEN + q) * D_MODEL + h * DHEAD + d] = f2bf(of[nt][rr]);
        }
    }
}

extern "C" void kernel_launch(void* const* d_in, const int* in_sizes, int n_in,
                              void* d_out, int out_size, void* d_ws, size_t ws_size,
                              hipStream_t stream)
{
    const float* q    = (const float*)d_in[0];
    const float* k    = (const float*)d_in[1];
    const float* v    = (const float*)d_in[2];
    // d_in[3] = causal mask — implemented analytically
    const float* wq_w = (const float*)d_in[4];
    const float* wq_b = (const float*)d_in[5];
    const float* wk_w = (const float*)d_in[6];
    const float* wk_b = (const float*)d_in[7];
    const float* wv_w = (const float*)d_in[8];
    const float* wv_b = (const float*)d_in[9];
    const float* wo_w = (const float*)d_in[10];
    const float* wo_b = (const float*)d_in[11];

    char* ws = (char*)d_ws;
    const size_t MB = 1024 * 1024;
    unsigned short* qb  = (unsigned short*)(ws + 0 * MB);
    unsigned short* kb  = (unsigned short*)(ws + 8 * MB);
    unsigned short* vb  = (unsigned short*)(ws + 16 * MB);
    unsigned short* wqb = (unsigned short*)(ws + 24 * MB);
    unsigned short* wkb = (unsigned short*)(ws + 26 * MB);
    unsigned short* wvb = (unsigned short*)(ws + 28 * MB);
    unsigned short* wob = (unsigned short*)(ws + 30 * MB);
    unsigned short* Qhp = (unsigned short*)(ws + 32 * MB);
    unsigned short* Khp = (unsigned short*)(ws + 40 * MB);
    unsigned short* Vtp = (unsigned short*)(ws + 48 * MB);
    unsigned short* ctx = (unsigned short*)(ws + 56 * MB);

    float* yout = (float*)d_out;
    float* attn = yout + (size_t)M_ROWS * D_MODEL;

    auto cvt = [&](const float* s, unsigned short* dptr, int n) {
        int n4 = n >> 2;
        cvt_kernel<<<dim3((n4 + 255) / 256), dim3(256), 0, stream>>>(s, dptr, n4);
    };
    cvt(q, qb, M_ROWS * D_MODEL);
    cvt(k, kb, M_ROWS * D_MODEL);
    cvt(v, vb, M_ROWS * D_MODEL);
    cvt(wq_w, wqb, D_MODEL * D_MODEL);
    cvt(wk_w, wkb, D_MODEL * D_MODEL);
    cvt(wv_w, wvb, D_MODEL * D_MODEL);
    cvt(wo_w, wob, D_MODEL * D_MODEL);

    dim3 blk(256);
    // Q,K: [4096,1024]x[1024,1024]^T -> head-major
    gemm_bt<0><<<dim3(8, 32), blk, 0, stream>>>(qb, wqb, wq_b, Qhp, M_ROWS, D_MODEL, D_MODEL);
    gemm_bt<0><<<dim3(8, 32), blk, 0, stream>>>(kb, wkb, wk_b, Khp, M_ROWS, D_MODEL, D_MODEL);
    // V transposed: A=wv (rows=d_full), B=v (rows=b*S+s) -> Vt [BH][64][S]
    gemm_bt<1><<<dim3(32, 8), blk, 0, stream>>>(wvb, vb, wv_b, Vtp, D_MODEL, M_ROWS, D_MODEL);
    attn_kernel<<<dim3(32, 32), blk, 0, stream>>>(Qhp, Khp, Vtp, attn, ctx);
    // final: y = ctx @ wo^T + b
    gemm_bt<2><<<dim3(8, 32), blk, 0, stream>>>(ctx, wob, wo_b, yout, M_ROWS, D_MODEL, D_MODEL);
}

// Round 2
// 487.785 us; speedup vs baseline: 1.0784x; 1.0784x over previous
//
#include <hip/hip_runtime.h>
#include <cstdint>

#define S_LEN   2048
#define D_MODEL 1024
#define NHEAD   16
#define DHEAD   64
#define BATCH   2
#define M_ROWS  (BATCH * S_LEN)   // 4096

typedef __attribute__((ext_vector_type(8))) short bf16x8;
typedef __attribute__((ext_vector_type(4))) float f32x4;

__device__ __forceinline__ unsigned short f2bf(float f) {
    union { float f; uint32_t u; } v; v.f = f;
    uint32_t u = v.u;
    return (unsigned short)((u + 0x7FFFu + ((u >> 16) & 1u)) >> 16);
}

// pack two f32 -> dword of 2 bf16 (RNE), single instruction
__device__ __forceinline__ uint32_t cvt_pk_bf16(float a, float b) {
    uint32_t r;
    asm("v_cvt_pk_bf16_f32 %0, %1, %2" : "=v"(r) : "v"(a), "v"(b));
    return r;
}

__device__ __forceinline__ void gload_lds16(const void* g, void* l) {
    __builtin_amdgcn_global_load_lds(
        (const __attribute__((address_space(1))) void*)g,
        (__attribute__((address_space(3))) void*)l, 16, 0, 0);
}

// ---------------- fused f32 -> bf16 convert (all 7 tensors, one launch) ----
struct CvtArgs {
    const float* src[7];
    unsigned short* dst[7];
    int n4[7];
};
__global__ __launch_bounds__(256) void cvt_all(CvtArgs a) {
    const int which = blockIdx.y;
    const int t = blockIdx.x * 256 + threadIdx.x;
    if (t >= a.n4[which]) return;
    f32x4 v = reinterpret_cast<const f32x4*>(a.src[which])[t];
    uint2 o;
    o.x = cvt_pk_bf16(v[0], v[1]);
    o.y = cvt_pk_bf16(v[2], v[3]);
    reinterpret_cast<uint2*>(a.dst[which])[t] = o;
}

// ---------------- GEMM: C = A @ Bw^T + bias ----------------
// A [M][K] bf16 row-major, Bw [N][K] bf16 row-major.
// MODE 0: out bf16, head-major [BH][S][DHEAD], scaled by prescale (Q,K proj)
// MODE 1: out bf16, V-transposed [BH][DHEAD][S] (bias[m])
// MODE 2: out f32 plain [M][N]                  (final y)
template<int MODE>
__global__ __launch_bounds__(256) void gemm_bt(
    const unsigned short* __restrict__ A,
    const unsigned short* __restrict__ Bw,
    const float* __restrict__ bias,
    void* __restrict__ Cout,
    int M, int N, int K, float prescale)
{
    __shared__ unsigned short lA[128 * 32];
    __shared__ unsigned short lB[128 * 32];
    const int tid  = threadIdx.x;
    const int lane = tid & 63;
    const int w    = tid >> 6;
    const int wr   = w >> 1, wc = w & 1;
    const int g    = lane >> 4, r16 = lane & 15;
    const int brow = blockIdx.y * 128;
    const int bcol = blockIdx.x * 128;

    f32x4 acc[4][4];
#pragma unroll
    for (int i = 0; i < 4; ++i)
#pragma unroll
        for (int j = 0; j < 4; ++j) acc[i][j] = (f32x4){0.f, 0.f, 0.f, 0.f};

    const int rA0 = tid >> 2;
    const int cc  = (tid & 3) * 8;

    for (int kk = 0; kk < K; kk += 32) {
#pragma unroll
        for (int it = 0; it < 2; ++it) {
            int r = it * 64 + rA0;
            gload_lds16(A  + (size_t)(brow + r) * K + kk + cc, &lA[r * 32 + cc]);
            gload_lds16(Bw + (size_t)(bcol + r) * K + kk + cc, &lB[r * 32 + cc]);
        }
        __syncthreads();
        bf16x8 af[4], bfr[4];
#pragma unroll
        for (int i = 0; i < 4; ++i)
            af[i] = *reinterpret_cast<const bf16x8*>(&lA[(wr * 64 + i * 16 + r16) * 32 + g * 8]);
#pragma unroll
        for (int j = 0; j < 4; ++j)
            bfr[j] = *reinterpret_cast<const bf16x8*>(&lB[(wc * 64 + j * 16 + r16) * 32 + g * 8]);
#pragma unroll
        for (int i = 0; i < 4; ++i)
#pragma unroll
            for (int j = 0; j < 4; ++j)
                acc[i][j] = __builtin_amdgcn_mfma_f32_16x16x32_bf16(af[i], bfr[j], acc[i][j], 0, 0, 0);
        __syncthreads();
    }

#pragma unroll
    for (int i = 0; i < 4; ++i) {
#pragma unroll
        for (int j = 0; j < 4; ++j) {
            const int n = bcol + wc * 64 + j * 16 + r16;
#pragma unroll
            for (int rr = 0; rr < 4; ++rr) {
                const int m = brow + wr * 64 + i * 16 + g * 4 + rr;
                float val = acc[i][j][rr];
                if (MODE == 0) {
                    val = (val + bias[n]) * prescale;
                    int b = m >> 11, s = m & 2047;
                    int h = n >> 6,  d = n & 63;
                    ((unsigned short*)Cout)[(((size_t)(b * NHEAD + h)) * S_LEN + s) * DHEAD + d] = f2bf(val);
                } else if (MODE == 1) {
                    val += bias[m];
                    int h = m >> 6,  d = m & 63;
                    int b = n >> 11, s = n & 2047;
                    ((unsigned short*)Cout)[(((size_t)(b * NHEAD + h)) * DHEAD + d) * S_LEN + s] = f2bf(val);
                } else {
                    val += bias[n];
                    ((float*)Cout)[(size_t)m * D_MODEL + n] = val;
                }
            }
        }
    }
}

// ---------------- fused causal attention ----------------
// Swapped-operand layout: lane holds one q-row (q = qw + r16), 16 k-scores.
// grid: (S/64 q-tiles reversed, B*H). 4 waves x 16 q-rows. Two-pass softmax.
__global__ __launch_bounds__(256) void attn_kernel(
    const unsigned short* __restrict__ Qh,
    const unsigned short* __restrict__ Kh,
    const unsigned short* __restrict__ Vt,
    float* __restrict__ attn_out,
    unsigned short* __restrict__ ctx)
{
    __shared__ unsigned short pS[4][16 * 72];   // per-wave P tile [q=16][k=64], stride 72
    const int tid  = threadIdx.x;
    const int lane = tid & 63;
    const int w    = tid >> 6;
    const int g    = lane >> 4, r16 = lane & 15;
    const int bh   = blockIdx.y;
    const int b    = bh >> 4, h = bh & 15;
    const int qtile = gridDim.x - 1 - blockIdx.x;   // heavy tiles dispatch first
    const int qw   = qtile * 64 + w * 16;
    const int qrel = w * 16 + r16;                  // q - qtile*64 (for diagonal mask)

    const unsigned short* Qp = Qh + ((size_t)bh * S_LEN + qw) * DHEAD;
    const unsigned short* Kp = Kh + (size_t)bh * S_LEN * DHEAD;
    const unsigned short* Vp = Vt + (size_t)bh * DHEAD * S_LEN;
    float* arow = attn_out + (size_t)bh * S_LEN * S_LEN;

    bf16x8 qf[2];
#pragma unroll
    for (int d2 = 0; d2 < 2; ++d2)
        qf[d2] = *reinterpret_cast<const bf16x8*>(Qp + (size_t)r16 * DHEAD + d2 * 32 + g * 8);

    unsigned short* pl = pS[w];

    // swapped QK^T: sf[nt][rr] = score(q = qw+r16, k = kb + nt*16 + g*4 + rr)
    auto qkt = [&](int kb, bool masked, f32x4 (&sf)[4]) {
#pragma unroll
        for (int nt = 0; nt < 4; ++nt) sf[nt] = (f32x4){0, 0, 0, 0};
#pragma unroll
        for (int d2 = 0; d2 < 2; ++d2)
#pragma unroll
            for (int nt = 0; nt < 4; ++nt) {
                bf16x8 kf = *reinterpret_cast<const bf16x8*>(
                    Kp + (size_t)(kb + nt * 16 + r16) * DHEAD + d2 * 32 + g * 8);
                sf[nt] = __builtin_amdgcn_mfma_f32_16x16x32_bf16(kf, qf[d2], sf[nt], 0, 0, 0);
            }
        if (masked) {
#pragma unroll
            for (int nt = 0; nt < 4; ++nt)
#pragma unroll
                for (int rr = 0; rr < 4; ++rr)
                    sf[nt][rr] = (nt * 16 + g * 4 + rr <= qrel) ? sf[nt][rr] : -1.0e30f;
        }
    };

    // ---- pass 1: per-lane (m,l) over this lane's k-subset; no cross-lane ----
    float m_run = -3.0e38f, l_run = 0.f;
    for (int kt = 0; kt <= qtile; ++kt) {
        f32x4 sf[4];
        qkt(kt * 64, kt == qtile, sf);
        float tmax = sf[0][0];
#pragma unroll
        for (int nt = 0; nt < 4; ++nt)
#pragma unroll
            for (int rr = 0; rr < 4; ++rr) tmax = fmaxf(tmax, sf[nt][rr]);
        float mn = fmaxf(m_run, tmax);
        float sum = 0.f;
#pragma unroll
        for (int nt = 0; nt < 4; ++nt)
#pragma unroll
            for (int rr = 0; rr < 4; ++rr)
                sum += __builtin_amdgcn_exp2f(sf[nt][rr] - mn);
        l_run = l_run * __builtin_amdgcn_exp2f(m_run - mn) + sum;
        m_run = mn;
    }
    // merge the 4 g-lanes' partial (m,l) -> m' = m + log2(l)
    float mo = fmaxf(m_run, __shfl_xor(m_run, 16));
    mo = fmaxf(mo, __shfl_xor(mo, 32));
    float lx = l_run * __builtin_amdgcn_exp2f(m_run - mo);
    lx += __shfl_xor(lx, 16);
    lx += __shfl_xor(lx, 32);
    const float mprime = mo + __builtin_amdgcn_logf(lx);

    f32x4 of[4];
#pragma unroll
    for (int nt = 0; nt < 4; ++nt) of[nt] = (f32x4){0, 0, 0, 0};

    // ---- pass 2: P = exp2(s - m'), store f32 probs, P@V via wave-private LDS ----
    for (int kt = 0; kt <= qtile; ++kt) {
        const int kb = kt * 64;
        const bool masked = (kt == qtile);
        f32x4 sf[4];
        qkt(kb, false, sf);
#pragma unroll
        for (int nt = 0; nt < 4; ++nt)
#pragma unroll
            for (int rr = 0; rr < 4; ++rr) {
                float p = __builtin_amdgcn_exp2f(sf[nt][rr] - mprime);
                if (masked) p = (nt * 16 + g * 4 + rr <= qrel) ? p : 0.f;
                sf[nt][rr] = p;
            }
        float* dst = arow + (size_t)(qw + r16) * S_LEN + kb + g * 4;
#pragma unroll
        for (int nt = 0; nt < 4; ++nt)
            __builtin_nontemporal_store(sf[nt], reinterpret_cast<f32x4*>(dst + nt * 16));
        // pack to bf16, write P^T tile [q][k] (wave-private, no block barrier)
#pragma unroll
        for (int nt = 0; nt < 4; ++nt) {
            uint2 pk2;
            pk2.x = cvt_pk_bf16(sf[nt][0], sf[nt][1]);
            pk2.y = cvt_pk_bf16(sf[nt][2], sf[nt][3]);
            *reinterpret_cast<uint2*>(&pl[r16 * 72 + nt * 16 + g * 4]) = pk2;
        }
        __builtin_amdgcn_wave_barrier();
#pragma unroll
        for (int kh = 0; kh < 2; ++kh) {
            bf16x8 pa = *reinterpret_cast<const bf16x8*>(&pl[r16 * 72 + kh * 32 + g * 8]);
#pragma unroll
            for (int nt = 0; nt < 4; ++nt) {
                bf16x8 vf = *reinterpret_cast<const bf16x8*>(
                    Vp + (size_t)(nt * 16 + r16) * S_LEN + kb + kh * 32 + g * 8);
                // swapped PV: rows = d, cols = q
                of[nt] = __builtin_amdgcn_mfma_f32_16x16x32_bf16(vf, pa, of[nt], 0, 0, 0);
            }
        }
        __builtin_amdgcn_wave_barrier();
    }

    // zero-fill strict upper region beyond the diagonal tile
    const int z0 = (qtile + 1) * 64;
    const f32x4 z4 = (f32x4){0.f, 0.f, 0.f, 0.f};
    for (int r = 0; r < 16; ++r) {
        float* dst = arow + (size_t)(qw + r) * S_LEN;
        for (int c = z0 + lane * 4; c < S_LEN; c += 256)
            __builtin_nontemporal_store(z4, reinterpret_cast<f32x4*>(dst + c));
    }

    // context out: of[nt][rr] = O^T[d = nt*16 + g*4 + rr][q = qw + r16]
    const size_t crow = ((size_t)b * S_LEN + qw + r16) * D_MODEL + h * DHEAD;
#pragma unroll
    for (int nt = 0; nt < 4; ++nt) {
        uint2 pk2;
        pk2.x = cvt_pk_bf16(of[nt][0], of[nt][1]);
        pk2.y = cvt_pk_bf16(of[nt][2], of[nt][3]);
        *reinterpret_cast<uint2*>(&ctx[crow + nt * 16 + g * 4]) = pk2;
    }
}

extern "C" void kernel_launch(void* const* d_in, const int* in_sizes, int n_in,
                              void* d_out, int out_size, void* d_ws, size_t ws_size,
                              hipStream_t stream)
{
    const float* q    = (const float*)d_in[0];
    const float* k    = (const float*)d_in[1];
    const float* v    = (const float*)d_in[2];
    const float* wq_w = (const float*)d_in[4];
    const float* wq_b = (const float*)d_in[5];
    const float* wk_w = (const float*)d_in[6];
    const float* wk_b = (const float*)d_in[7];
    const float* wv_w = (const float*)d_in[8];
    const float* wv_b = (const float*)d_in[9];
    const float* wo_w = (const float*)d_in[10];
    const float* wo_b = (const float*)d_in[11];

    char* ws = (char*)d_ws;
    const size_t MB = 1024 * 1024;
    unsigned short* qb  = (unsigned short*)(ws + 0 * MB);
    unsigned short* kb  = (unsigned short*)(ws + 8 * MB);
    unsigned short* vb  = (unsigned short*)(ws + 16 * MB);
    unsigned short* wqb = (unsigned short*)(ws + 24 * MB);
    unsigned short* wkb = (unsigned short*)(ws + 26 * MB);
    unsigned short* wvb = (unsigned short*)(ws + 28 * MB);
    unsigned short* wob = (unsigned short*)(ws + 30 * MB);
    unsigned short* Qhp = (unsigned short*)(ws + 32 * MB);
    unsigned short* Khp = (unsigned short*)(ws + 40 * MB);
    unsigned short* Vtp = (unsigned short*)(ws + 48 * MB);
    unsigned short* ctx = (unsigned short*)(ws + 56 * MB);

    float* yout = (float*)d_out;
    float* attn = yout + (size_t)M_ROWS * D_MODEL;

    CvtArgs ca;
    ca.src[0] = q;    ca.dst[0] = qb;  ca.n4[0] = M_ROWS * D_MODEL / 4;
    ca.src[1] = k;    ca.dst[1] = kb;  ca.n4[1] = M_ROWS * D_MODEL / 4;
    ca.src[2] = v;    ca.dst[2] = vb;  ca.n4[2] = M_ROWS * D_MODEL / 4;
    ca.src[3] = wq_w; ca.dst[3] = wqb; ca.n4[3] = D_MODEL * D_MODEL / 4;
    ca.src[4] = wk_w; ca.dst[4] = wkb; ca.n4[4] = D_MODEL * D_MODEL / 4;
    ca.src[5] = wv_w; ca.dst[5] = wvb; ca.n4[5] = D_MODEL * D_MODEL / 4;
    ca.src[6] = wo_w; ca.dst[6] = wob; ca.n4[6] = D_MODEL * D_MODEL / 4;
    cvt_all<<<dim3((M_ROWS * D_MODEL / 4 + 255) / 256, 7), dim3(256), 0, stream>>>(ca);

    dim3 blk(256);
    // fold score-scale * log2(e) into Q
    const float qscale = 0.125f * 1.44269504088896340736f;
    gemm_bt<0><<<dim3(8, 32), blk, 0, stream>>>(qb, wqb, wq_b, Qhp, M_ROWS, D_MODEL, D_MODEL, qscale);
    gemm_bt<0><<<dim3(8, 32), blk, 0, stream>>>(kb, wkb, wk_b, Khp, M_ROWS, D_MODEL, D_MODEL, 1.0f);
    gemm_bt<1><<<dim3(32, 8), blk, 0, stream>>>(wvb, vb, wv_b, Vtp, D_MODEL, M_ROWS, D_MODEL, 1.0f);
    attn_kernel<<<dim3(32, 32), blk, 0, stream>>>(Qhp, Khp, Vtp, attn, ctx);
    gemm_bt<2><<<dim3(8, 32), blk, 0, stream>>>(ctx, wob, wo_b, yout, M_ROWS, D_MODEL, D_MODEL, 1.0f);
}

// Round 3
// 330.653 us; speedup vs baseline: 1.5909x; 1.4752x over previous
//
#include <hip/hip_runtime.h>
#include <cstdint>

#define S_LEN   2048
#define D_MODEL 1024
#define NHEAD   16
#define DHEAD   64
#define BATCH   2
#define M_ROWS  (BATCH * S_LEN)   // 4096

typedef __attribute__((ext_vector_type(8))) short bf16x8;
typedef __attribute__((ext_vector_type(4))) float f32x4;

__device__ __forceinline__ unsigned short f2bf(float f) {
    union { float f; uint32_t u; } v; v.f = f;
    uint32_t u = v.u;
    return (unsigned short)((u + 0x7FFFu + ((u >> 16) & 1u)) >> 16);
}

__device__ __forceinline__ float bf2f(uint32_t u16) {
    union { uint32_t u; float f; } x; x.u = u16 << 16; return x.f;
}

// pack two f32 -> dword of 2 bf16 (RNE), single instruction
__device__ __forceinline__ uint32_t cvt_pk_bf16(float a, float b) {
    uint32_t r;
    asm("v_cvt_pk_bf16_f32 %0, %1, %2" : "=v"(r) : "v"(a), "v"(b));
    return r;
}

__device__ __forceinline__ void gload_lds16(const void* g, void* l) {
    __builtin_amdgcn_global_load_lds(
        (const __attribute__((address_space(1))) void*)g,
        (__attribute__((address_space(3))) void*)l, 16, 0, 0);
}

// ---------------- fused f32 -> bf16 convert (all 7 tensors, one launch) ----
struct CvtArgs {
    const float* src[7];
    unsigned short* dst[7];
    int n4[7];
};
__global__ __launch_bounds__(256) void cvt_all(CvtArgs a) {
    const int which = blockIdx.y;
    const int t = blockIdx.x * 256 + threadIdx.x;
    if (t >= a.n4[which]) return;
    f32x4 v = reinterpret_cast<const f32x4*>(a.src[which])[t];
    uint2 o;
    o.x = cvt_pk_bf16(v[0], v[1]);
    o.y = cvt_pk_bf16(v[2], v[3]);
    reinterpret_cast<uint2*>(a.dst[which])[t] = o;
}

// ---------------- GEMM: C = A @ Bw^T + bias ----------------
template<int MODE>
__global__ __launch_bounds__(256) void gemm_bt(
    const unsigned short* __restrict__ A,
    const unsigned short* __restrict__ Bw,
    const float* __restrict__ bias,
    void* __restrict__ Cout,
    int M, int N, int K, float prescale)
{
    __shared__ unsigned short lA[128 * 32];
    __shared__ unsigned short lB[128 * 32];
    const int tid  = threadIdx.x;
    const int lane = tid & 63;
    const int w    = tid >> 6;
    const int wr   = w >> 1, wc = w & 1;
    const int g    = lane >> 4, r16 = lane & 15;
    const int brow = blockIdx.y * 128;
    const int bcol = blockIdx.x * 128;

    f32x4 acc[4][4];
#pragma unroll
    for (int i = 0; i < 4; ++i)
#pragma unroll
        for (int j = 0; j < 4; ++j) acc[i][j] = (f32x4){0.f, 0.f, 0.f, 0.f};

    const int rA0 = tid >> 2;
    const int cc  = (tid & 3) * 8;

    for (int kk = 0; kk < K; kk += 32) {
#pragma unroll
        for (int it = 0; it < 2; ++it) {
            int r = it * 64 + rA0;
            gload_lds16(A  + (size_t)(brow + r) * K + kk + cc, &lA[r * 32 + cc]);
            gload_lds16(Bw + (size_t)(bcol + r) * K + kk + cc, &lB[r * 32 + cc]);
        }
        __syncthreads();
        bf16x8 af[4], bfr[4];
#pragma unroll
        for (int i = 0; i < 4; ++i)
            af[i] = *reinterpret_cast<const bf16x8*>(&lA[(wr * 64 + i * 16 + r16) * 32 + g * 8]);
#pragma unroll
        for (int j = 0; j < 4; ++j)
            bfr[j] = *reinterpret_cast<const bf16x8*>(&lB[(wc * 64 + j * 16 + r16) * 32 + g * 8]);
#pragma unroll
        for (int i = 0; i < 4; ++i)
#pragma unroll
            for (int j = 0; j < 4; ++j)
                acc[i][j] = __builtin_amdgcn_mfma_f32_16x16x32_bf16(af[i], bfr[j], acc[i][j], 0, 0, 0);
        __syncthreads();
    }

#pragma unroll
    for (int i = 0; i < 4; ++i) {
#pragma unroll
        for (int j = 0; j < 4; ++j) {
            const int n = bcol + wc * 64 + j * 16 + r16;
#pragma unroll
            for (int rr = 0; rr < 4; ++rr) {
                const int m = brow + wr * 64 + i * 16 + g * 4 + rr;
                float val = acc[i][j][rr];
                if (MODE == 0) {
                    val = (val + bias[n]) * prescale;
                    int b = m >> 11, s = m & 2047;
                    int h = n >> 6,  d = n & 63;
                    ((unsigned short*)Cout)[(((size_t)(b * NHEAD + h)) * S_LEN + s) * DHEAD + d] = f2bf(val);
                } else if (MODE == 1) {
                    val += bias[m];
                    int h = m >> 6,  d = m & 63;
                    int b = n >> 11, s = n & 2047;
                    ((unsigned short*)Cout)[(((size_t)(b * NHEAD + h)) * DHEAD + d) * S_LEN + s] = f2bf(val);
                } else {
                    val += bias[n];
                    ((float*)Cout)[(size_t)m * D_MODEL + n] = val;
                }
            }
        }
    }
}

// ---------------- fused causal attention (balanced, pipelined) ----------------
// 512 threads = 8 waves. Waves 0-3: qtile 16+x (heavy); waves 4-7: qtile 15-x.
// Every block: 33 tile-iters per pass + 31 zero tiles -> perfectly balanced grid.
// Wave-private ping-pong P LDS, no barriers; coalesced f32 P stores via LDS.
__global__ __launch_bounds__(512, 4) void attn_kernel(
    const unsigned short* __restrict__ Qh,
    const unsigned short* __restrict__ Kh,
    const unsigned short* __restrict__ Vt,
    float* __restrict__ attn_out,
    unsigned short* __restrict__ ctx)
{
    __shared__ unsigned short pS[8][2][16 * 72];   // per-wave ping-pong P tile
    const int tid  = threadIdx.x;
    const int lane = tid & 63;
    const int w    = tid >> 6;          // 0..7
    const int grp  = w >> 2;            // 0 = heavy group, 1 = light group
    const int wg   = w & 3;             // wave within group
    const int g    = lane >> 4, r16 = lane & 15;
    const int bh   = blockIdx.y;
    const int b    = bh >> 4, h = bh & 15;
    const int qtile = (grp == 0) ? (16 + (int)blockIdx.x) : (15 - (int)blockIdx.x);
    const int qw   = qtile * 64 + wg * 16;
    const int qrel = wg * 16 + r16;     // q - qtile*64 (diagonal mask)

    const unsigned short* Qp = Qh + ((size_t)bh * S_LEN + qw) * DHEAD;
    const unsigned short* Kp = Kh + (size_t)bh * S_LEN * DHEAD;
    const unsigned short* Vp = Vt + (size_t)bh * DHEAD * S_LEN;
    float* arow = attn_out + (size_t)bh * S_LEN * S_LEN;

    bf16x8 qf[2];
#pragma unroll
    for (int d2 = 0; d2 < 2; ++d2)
        qf[d2] = *reinterpret_cast<const bf16x8*>(Qp + (size_t)r16 * DHEAD + d2 * 32 + g * 8);

    // swapped QK^T: sf[nt][rr] = score(q = qw+r16, k = kb + nt*16 + g*4 + rr)
    auto qkt = [&](int kb, bool masked, f32x4 (&sf)[4]) {
#pragma unroll
        for (int nt = 0; nt < 4; ++nt) sf[nt] = (f32x4){0, 0, 0, 0};
#pragma unroll
        for (int d2 = 0; d2 < 2; ++d2)
#pragma unroll
            for (int nt = 0; nt < 4; ++nt) {
                bf16x8 kf = *reinterpret_cast<const bf16x8*>(
                    Kp + (size_t)(kb + nt * 16 + r16) * DHEAD + d2 * 32 + g * 8);
                sf[nt] = __builtin_amdgcn_mfma_f32_16x16x32_bf16(kf, qf[d2], sf[nt], 0, 0, 0);
            }
        if (masked) {
#pragma unroll
            for (int nt = 0; nt < 4; ++nt)
#pragma unroll
                for (int rr = 0; rr < 4; ++rr)
                    sf[nt][rr] = (nt * 16 + g * 4 + rr <= qrel) ? sf[nt][rr] : -1.0e30f;
        }
    };

    // ---- pass 1: per-lane (m,l); cross-lane merge only at the end ----
    float m_run = -3.0e38f, l_run = 0.f;
    for (int kt = 0; kt <= qtile; ++kt) {
        f32x4 sf[4];
        qkt(kt * 64, kt == qtile, sf);
        float tmax = sf[0][0];
#pragma unroll
        for (int nt = 0; nt < 4; ++nt)
#pragma unroll
            for (int rr = 0; rr < 4; ++rr) tmax = fmaxf(tmax, sf[nt][rr]);
        float mn = fmaxf(m_run, tmax);
        float sum = 0.f;
#pragma unroll
        for (int nt = 0; nt < 4; ++nt)
#pragma unroll
            for (int rr = 0; rr < 4; ++rr)
                sum += __builtin_amdgcn_exp2f(sf[nt][rr] - mn);
        l_run = l_run * __builtin_amdgcn_exp2f(m_run - mn) + sum;
        m_run = mn;
    }
    float mo = fmaxf(m_run, __shfl_xor(m_run, 16));
    mo = fmaxf(mo, __shfl_xor(mo, 32));
    float lx = l_run * __builtin_amdgcn_exp2f(m_run - mo);
    lx += __shfl_xor(lx, 16);
    lx += __shfl_xor(lx, 32);
    const float mprime = mo + __builtin_amdgcn_logf(lx);   // log2

    f32x4 of[4];
#pragma unroll
    for (int nt = 0; nt < 4; ++nt) of[nt] = (f32x4){0, 0, 0, 0};

    const int rl = lane >> 4;        // P-store: row sub-index
    const int c4 = (lane & 15) * 4;  // P-store: col within tile

    // ---- pass 2: P = exp2(s - m'), P@V, coalesced f32 P store ----
    for (int kt = 0; kt <= qtile; ++kt) {
        const int kb = kt * 64;
        const bool masked = (kt == qtile);
        unsigned short* pl = pS[w][kt & 1];
        f32x4 sf[4];
        qkt(kb, false, sf);
#pragma unroll
        for (int nt = 0; nt < 4; ++nt)
#pragma unroll
            for (int rr = 0; rr < 4; ++rr) {
                float p = __builtin_amdgcn_exp2f(sf[nt][rr] - mprime);
                if (masked) p = (nt * 16 + g * 4 + rr <= qrel) ? p : 0.f;
                sf[nt][rr] = p;
            }
        // pack to bf16 P^T tile [q=16][k=64] (wave-private)
#pragma unroll
        for (int nt = 0; nt < 4; ++nt) {
            uint2 pk2;
            pk2.x = cvt_pk_bf16(sf[nt][0], sf[nt][1]);
            pk2.y = cvt_pk_bf16(sf[nt][2], sf[nt][3]);
            *reinterpret_cast<uint2*>(&pl[r16 * 72 + nt * 16 + g * 4]) = pk2;
        }
        // P@V (swapped: rows = d, cols = q)
#pragma unroll
        for (int kh = 0; kh < 2; ++kh) {
            bf16x8 pa = *reinterpret_cast<const bf16x8*>(&pl[r16 * 72 + kh * 32 + g * 8]);
#pragma unroll
            for (int nt = 0; nt < 4; ++nt) {
                bf16x8 vf = *reinterpret_cast<const bf16x8*>(
                    Vp + (size_t)(nt * 16 + r16) * S_LEN + kb + kh * 32 + g * 8);
                of[nt] = __builtin_amdgcn_mfma_f32_16x16x32_bf16(vf, pa, of[nt], 0, 0, 0);
            }
        }
        // coalesced f32 P store: 4 instrs x (4 rows x 256B contiguous)
        float* dst0 = arow + (size_t)qw * S_LEN + kb;
#pragma unroll
        for (int i = 0; i < 4; ++i) {
            const int r = i * 4 + rl;
            uint2 dpk = *reinterpret_cast<const uint2*>(&pl[r * 72 + c4]);
            f32x4 o;
            o[0] = bf2f(dpk.x & 0xffffu);
            o[1] = bf2f(dpk.x >> 16);
            o[2] = bf2f(dpk.y & 0xffffu);
            o[3] = bf2f(dpk.y >> 16);
            __builtin_nontemporal_store(o, reinterpret_cast<f32x4*>(dst0 + (size_t)r * S_LEN + c4));
        }
    }

    // zero-fill strict upper region beyond the diagonal tile
    const int z0 = (qtile + 1) * 64;
    const f32x4 z4 = (f32x4){0.f, 0.f, 0.f, 0.f};
    for (int r = 0; r < 16; ++r) {
        float* dst = arow + (size_t)(qw + r) * S_LEN;
        for (int c = z0 + lane * 4; c < S_LEN; c += 256)
            __builtin_nontemporal_store(z4, reinterpret_cast<f32x4*>(dst + c));
    }

    // context out: of[nt][rr] = O^T[d = nt*16 + g*4 + rr][q = qw + r16]
    const size_t crow = ((size_t)b * S_LEN + qw + r16) * D_MODEL + h * DHEAD;
#pragma unroll
    for (int nt = 0; nt < 4; ++nt) {
        uint2 pk2;
        pk2.x = cvt_pk_bf16(of[nt][0], of[nt][1]);
        pk2.y = cvt_pk_bf16(of[nt][2], of[nt][3]);
        *reinterpret_cast<uint2*>(&ctx[crow + nt * 16 + g * 4]) = pk2;
    }
}

extern "C" void kernel_launch(void* const* d_in, const int* in_sizes, int n_in,
                              void* d_out, int out_size, void* d_ws, size_t ws_size,
                              hipStream_t stream)
{
    const float* q    = (const float*)d_in[0];
    const float* k    = (const float*)d_in[1];
    const float* v    = (const float*)d_in[2];
    const float* wq_w = (const float*)d_in[4];
    const float* wq_b = (const float*)d_in[5];
    const float* wk_w = (const float*)d_in[6];
    const float* wk_b = (const float*)d_in[7];
    const float* wv_w = (const float*)d_in[8];
    const float* wv_b = (const float*)d_in[9];
    const float* wo_w = (const float*)d_in[10];
    const float* wo_b = (const float*)d_in[11];

    char* ws = (char*)d_ws;
    const size_t MB = 1024 * 1024;
    unsigned short* qb  = (unsigned short*)(ws + 0 * MB);
    unsigned short* kb  = (unsigned short*)(ws + 8 * MB);
    unsigned short* vb  = (unsigned short*)(ws + 16 * MB);
    unsigned short* wqb = (unsigned short*)(ws + 24 * MB);
    unsigned short* wkb = (unsigned short*)(ws + 26 * MB);
    unsigned short* wvb = (unsigned short*)(ws + 28 * MB);
    unsigned short* wob = (unsigned short*)(ws + 30 * MB);
    unsigned short* Qhp = (unsigned short*)(ws + 32 * MB);
    unsigned short* Khp = (unsigned short*)(ws + 40 * MB);
    unsigned short* Vtp = (unsigned short*)(ws + 48 * MB);
    unsigned short* ctx = (unsigned short*)(ws + 56 * MB);

    float* yout = (float*)d_out;
    float* attn = yout + (size_t)M_ROWS * D_MODEL;

    CvtArgs ca;
    ca.src[0] = q;    ca.dst[0] = qb;  ca.n4[0] = M_ROWS * D_MODEL / 4;
    ca.src[1] = k;    ca.dst[1] = kb;  ca.n4[1] = M_ROWS * D_MODEL / 4;
    ca.src[2] = v;    ca.dst[2] = vb;  ca.n4[2] = M_ROWS * D_MODEL / 4;
    ca.src[3] = wq_w; ca.dst[3] = wqb; ca.n4[3] = D_MODEL * D_MODEL / 4;
    ca.src[4] = wk_w; ca.dst[4] = wkb; ca.n4[4] = D_MODEL * D_MODEL / 4;
    ca.src[5] = wv_w; ca.dst[5] = wvb; ca.n4[5] = D_MODEL * D_MODEL / 4;
    ca.src[6] = wo_w; ca.dst[6] = wob; ca.n4[6] = D_MODEL * D_MODEL / 4;
    cvt_all<<<dim3((M_ROWS * D_MODEL / 4 + 255) / 256, 7), dim3(256), 0, stream>>>(ca);

    dim3 blk(256);
    const float qscale = 0.125f * 1.44269504088896340736f;  // fold scale*log2(e) into Q
    gemm_bt<0><<<dim3(8, 32), blk, 0, stream>>>(qb, wqb, wq_b, Qhp, M_ROWS, D_MODEL, D_MODEL, qscale);
    gemm_bt<0><<<dim3(8, 32), blk, 0, stream>>>(kb, wkb, wk_b, Khp, M_ROWS, D_MODEL, D_MODEL, 1.0f);
    gemm_bt<1><<<dim3(32, 8), blk, 0, stream>>>(wvb, vb, wv_b, Vtp, D_MODEL, M_ROWS, D_MODEL, 1.0f);
    attn_kernel<<<dim3(16, 32), dim3(512), 0, stream>>>(Qhp, Khp, Vtp, attn, ctx);
    gemm_bt<2><<<dim3(8, 32), blk, 0, stream>>>(ctx, wob, wo_b, yout, M_ROWS, D_MODEL, D_MODEL, 1.0f);
}